// Round 13
// baseline (1395.316 us; speedup 1.0000x reference)
//
#include <hip/hip_runtime.h>

typedef unsigned short u16;
typedef unsigned int u32;
typedef __bf16 bf16x8 __attribute__((ext_vector_type(8)));
typedef float f32x4 __attribute__((ext_vector_type(4)));

#define N_NODES 32768
#define E_EDGES 262144
#define BQ_U16 26240    // one 80-col quarter of padded B: 80*328 u16 (52.5 KB)
#define S75 0.11547005383792515f

__device__ __forceinline__ float b2f(u16 u) {
    union { u32 u; float f; } x; x.u = ((u32)u) << 16; return x.f;
}
__device__ __forceinline__ u16 f2b(float f) {
    union { float f; u32 u; } x; x.f = f;
    u32 r = x.u + 0x7FFF + ((x.u >> 16) & 1);
    return (u16)(r >> 16);
}

#define GLOAD16(g, l) \
    __builtin_amdgcn_global_load_lds((const __attribute__((address_space(1))) u32*)(g), \
                                     (__attribute__((address_space(3))) u32*)(l), 16, 0, 0)

// ---------------- plain weight transpose (final 960-K projection) ----------------
__global__ void convT_k(const float* __restrict__ src, int R, int C,
                        u16* __restrict__ dst, int KP_, long total) {
    long id = (long)blockIdx.x * blockDim.x + threadIdx.x;
    if (id >= total) return;
    int n = (int)(id / KP_), k = (int)(id % KP_);
    dst[id] = (k < R && n < C) ? f2b(src[(long)k * C + n]) : (u16)0;
}

// ---------------- quarter-weight build: dst[q][r][c], c in [0,328) = W[c][q*80+r] ----------------
__global__ void convTq_k(const float* __restrict__ src, u16* __restrict__ dst) {
    int id = blockIdx.x * 256 + threadIdx.x;
    if (id >= 4 * BQ_U16) return;
    int q = id / BQ_U16, rem = id % BQ_U16;
    int r = rem / 328, c = rem % 328;
    int n = q * 80 + r;
    dst[id] = (c < 300 && n < 300) ? f2b(src[(long)c * 300 + n]) : (u16)0;
}

// ---------------- Wqk build (16 quarters of 80 cols, 328-padded K) ----------------
__global__ void wqkq_k(const float* __restrict__ Wq, const float* __restrict__ Wk,
                       u16* __restrict__ dst) {
    int id = blockIdx.x * 256 + threadIdx.x;
    if (id >= 16 * BQ_U16) return;
    int q = id / BQ_U16, rem = id % BQ_U16;
    int r = rem / 328, c = rem % 328;
    int h = q >> 2;
    int cc = (q & 3) * 80 + r;
    float acc = 0.f;
    if (c < 300 && cc < 300) {
        const float* wq = Wq + (long)c * 300 + 75 * h;
        const float* wk = Wk + (long)cc * 300 + 75 * h;
        for (int d = 0; d < 75; ++d) acc += wq[d] * wk[d];
        acc *= S75;
    }
    dst[id] = f2b(acc);
}

// bqk[320h+cc] = S75 * sum_d bq[75h+d]*Wk[cc,75h+d]
__global__ void bqk_k(const float* __restrict__ bq, const float* __restrict__ Wk,
                      float* __restrict__ dst) {
    int n = blockIdx.x * 256 + threadIdx.x;
    if (n >= 1280) return;
    int h = n / 320, cc = n % 320;
    float acc = 0.f;
    if (cc < 300) {
        const float* b = bq + 75 * h;
        const float* wk = Wk + (long)cc * 300 + 75 * h;
        for (int d = 0; d < 75; ++d) acc += b[d] * wk[d];
        acc *= S75;
    }
    dst[n] = acc;
}

// ---------------- phased Ucat build: dst[q][ph][r<80][c<328]; k = ph*320+c, n = q*80+r ----------------
__global__ void ucatp_k(const float* __restrict__ Wv, const float* __restrict__ Wo,
                        u16* __restrict__ dst) {
    long id = (long)blockIdx.x * 256 + threadIdx.x;
    if (id >= 4L * 5 * BQ_U16) return;
    int q = (int)(id / (5 * BQ_U16));
    int rem = (int)(id % (5 * BQ_U16));
    int ph = rem / BQ_U16;
    int rem2 = rem % BQ_U16;
    int r = rem2 / 328, c = rem2 % 328;
    int n = q * 80 + r;
    float acc = 0.f;
    if (n < 300 && c < 320) {
        if (ph < 4) {
            int a = c;                 // k = ph*320 + c, head = ph
            if (a < 300) {
                const float* wv = Wv + (long)a * 300 + 75 * ph;
                const float* wo = Wo + (long)(75 * ph) * 300 + n;
                for (int d = 0; d < 75; ++d) acc += wv[d] * wo[(long)d * 300];
            }
        } else {
            int a = c;                 // feat part: k = 1280 + c
            if (a < 300) {
                const float* wv = Wv + (long)a * 300;
                const float* wo = Wo + n;
                for (int d = 0; d < 300; ++d) acc += wv[d] * wo[(long)d * 300];
            }
        }
    }
    dst[id] = f2b(acc);
}

// bvo[n] = sum_d bv[d]*Wo[d,n] + bo[n]
__global__ void bvo_k(const float* __restrict__ bv, const float* __restrict__ Wo,
                      const float* __restrict__ bo, float* __restrict__ dst) {
    int n = blockIdx.x * 256 + threadIdx.x;
    if (n >= 320) return;
    float acc = 0.f;
    if (n < 300) {
        for (int d = 0; d < 300; ++d) acc += bv[d] * Wo[(long)d * 300 + n];
        acc += bo[n];
    }
    dst[n] = acc;
}

// ---------------- activation pad+convert ----------------
__global__ void padconv_k(const float* __restrict__ src, int C,
                          u16* __restrict__ dst, int CP,
                          u16* __restrict__ dst2, int CP2, long total) {
    long id = (long)blockIdx.x * blockDim.x + threadIdx.x;
    if (id >= total) return;
    int cw = CP >> 3;
    long row = id / cw;
    int c8 = (int)(id % cw) * 8;
    u32 w[4];
    #pragma unroll
    for (int p = 0; p < 4; ++p) {
        int c0 = c8 + 2 * p, c1 = c0 + 1;
        u16 lo = (c0 < C) ? f2b(src[row * C + c0]) : (u16)0;
        u16 hi = (c1 < C) ? f2b(src[row * C + c1]) : (u16)0;
        w[p] = (u32)lo | ((u32)hi << 16);
    }
    u32* d = (u32*)(dst + row * CP + c8);
    d[0] = w[0]; d[1] = w[1]; d[2] = w[2]; d[3] = w[3];
    if (dst2) {
        u32* d2 = (u32*)(dst2 + row * CP2 + c8);
        d2[0] = w[0]; d2[1] = w[1]; d2[2] = w[2]; d2[3] = w[3];
    }
}

// ---------------- feat copy: wideA[n][1280+c] = fhb[n][c] ----------------
__global__ void featcopy_k(const u16* __restrict__ src, u16* __restrict__ dst) {
    long id = (long)blockIdx.x * 256 + threadIdx.x;
    if (id >= (long)N_NODES * 40) return;
    long row = id / 40;
    int c8 = (int)(id % 40) * 8;
    *(uint4*)&dst[row * 1600 + 1280 + c8] = *(const uint4*)&src[row * 320 + c8];
}

// ================== tile compute macro: 128x80 block, 4 waves, acc[2][5] ==================
#define TCOMP(KB, APTR) do { \
    bf16x8 av_[2], bb_[5]; \
    _Pragma("unroll") for (int fr = 0; fr < 2; ++fr) \
        av_[fr] = *(const bf16x8*)&(APTR)[ar0 + fr * 512]; \
    _Pragma("unroll") for (int fc = 0; fc < 5; ++fc) \
        bb_[fc] = *(const bf16x8*)&Bs[br0 + fc * 5248 + (KB) * 32]; \
    __builtin_amdgcn_s_setprio(1); \
    _Pragma("unroll") for (int fr = 0; fr < 2; ++fr) \
        _Pragma("unroll") for (int fc = 0; fc < 5; ++fc) \
            acc[fr][fc] = __builtin_amdgcn_mfma_f32_16x16x32_bf16(bb_[fc], av_[fr], acc[fr][fc], 0, 0, 0); \
    __builtin_amdgcn_s_setprio(0); \
} while (0)

// ---------------- generic N-scale GEMM: out(M x OSTR) = A(M x 320) @ Bq (+bias), bf16 out ----------------
// 128 rows x 80 cols per block; 2^QBITS col-quarters; ESTEP pipeline (counted vmcnt, 3-buf A).
template<int QBITS, int OSTR>
__global__ __launch_bounds__(256, 2) void ngemm_k(
    const u16* __restrict__ A, const u16* __restrict__ Bswz,
    const float* __restrict__ bias, u16* __restrict__ outB)
{
    __shared__ __attribute__((aligned(16))) u16 Bs[80 * 328];
    __shared__ __attribute__((aligned(16))) u16 As3[3][128 * 32];
    const int tid = threadIdx.x;
    const int wf = tid >> 6, lane = tid & 63;
    const int tl = lane & 15, thi = lane >> 4;
    const int bid = blockIdx.x;
    const int gid = (bid & 7) * ((int)gridDim.x >> 3) + (bid >> 3);
    const long m0 = (long)(gid >> QBITS) * 128;
    const int q = gid & ((1 << QBITS) - 1);
    const int n0 = q * 80;
    const int wf_u = __builtin_amdgcn_readfirstlane(wf);
    const u16* Bsrc = Bswz + q * BQ_U16;

    #pragma unroll
    for (int i = 0; i < 13; ++i) {
        int t = i * 256 + tid;
        if (t < 3280)
            GLOAD16(Bsrc + (long)t * 8, &Bs[(i * 256 + wf_u * 64) * 8]);
    }
    const int r1 = tid >> 2;
    const int g1 = (tid & 3) ^ ((r1 >> 1) & 3);
    const u16* gA0 = A + (m0 + r1) * 320L + g1 * 8;
    const u16* gA1 = A + (m0 + 64 + r1) * 320L + g1 * 8;

#define ESTAGE(KB) { \
    GLOAD16(gA0 + (KB) * 32, &As3[(KB) % 3][wf_u * 512]); \
    GLOAD16(gA1 + (KB) * 32, &As3[(KB) % 3][2048 + wf_u * 512]); }

    ESTAGE(0); ESTAGE(1);

    f32x4 acc[2][5];
    #pragma unroll
    for (int i = 0; i < 2; ++i)
        #pragma unroll
        for (int j = 0; j < 5; ++j) acc[i][j] = (f32x4)(0.f);
    const int ar0 = (wf * 32 + tl) * 32 + (thi ^ ((tl >> 1) & 3)) * 8;
    const int br0 = tl * 328 + thi * 8;

#define ESTEP(KB, VN) { \
    asm volatile("s_waitcnt vmcnt(" #VN ")" ::: "memory"); \
    __builtin_amdgcn_s_barrier(); \
    __builtin_amdgcn_sched_barrier(0); \
    if ((KB) + 2 < 10) ESTAGE((KB) + 2); \
    TCOMP(KB, (&As3[(KB) % 3][0])); }

    ESTEP(0, 2) ESTEP(1, 2) ESTEP(2, 2) ESTEP(3, 2) ESTEP(4, 2)
    ESTEP(5, 2) ESTEP(6, 2) ESTEP(7, 2) ESTEP(8, 2) ESTEP(9, 0)
#undef ESTEP
#undef ESTAGE

    #pragma unroll
    for (int fr = 0; fr < 2; ++fr) {
        const long row = m0 + wf * 32 + fr * 16 + tl;
        #pragma unroll
        for (int fc = 0; fc < 5; ++fc) {
            const int c0 = n0 + fc * 16 + thi * 4;
            f32x4 v = acc[fr][fc];
            if (bias) {
                const float4 bs = *(const float4*)&bias[c0];
                v[0] += bs.x; v[1] += bs.y; v[2] += bs.z; v[3] += bs.w;
            }
            uint2 p;
            p.x = (u32)f2b(v[0]) | ((u32)f2b(v[1]) << 16);
            p.y = (u32)f2b(v[2]) | ((u32)f2b(v[3]) << 16);
            *(uint2*)&outB[row * (long)OSTR + c0] = p;
        }
    }
}

// ---------------- h-update dense GEMM: HG = hcur @ Wm ; epilogue does the gather+swap ----------------
// h'[e] = relu(x[e] + FG[src[e]] - HG[e^1] + bmp).  HG[e^1] comes from lane tl^1 via shfl.
__global__ __launch_bounds__(256, 2) void hgemm_k(
    const u16* __restrict__ A /*hcur*/, const u16* __restrict__ Bswz /*Wm quarters*/,
    const u16* __restrict__ FG, const u16* __restrict__ hx,
    const int* __restrict__ srcidx, const float* __restrict__ bias,
    u16* __restrict__ outB)
{
    __shared__ __attribute__((aligned(16))) u16 Bs[80 * 328];
    __shared__ __attribute__((aligned(16))) u16 As3[3][128 * 32];
    const int tid = threadIdx.x;
    const int wf = tid >> 6, lane = tid & 63;
    const int tl = lane & 15, thi = lane >> 4;
    const int bid = blockIdx.x;
    const int gid = (bid & 7) * ((int)gridDim.x >> 3) + (bid >> 3);
    const long m0 = (long)(gid >> 2) * 128;
    const int q = gid & 3;
    const int n0 = q * 80;
    const int wf_u = __builtin_amdgcn_readfirstlane(wf);
    const u16* Bsrc = Bswz + q * BQ_U16;

    #pragma unroll
    for (int i = 0; i < 13; ++i) {
        int t = i * 256 + tid;
        if (t < 3280)
            GLOAD16(Bsrc + (long)t * 8, &Bs[(i * 256 + wf_u * 64) * 8]);
    }
    const int r1 = tid >> 2;
    const int g1 = (tid & 3) ^ ((r1 >> 1) & 3);
    const u16* gA0 = A + (m0 + r1) * 320L + g1 * 8;
    const u16* gA1 = A + (m0 + 64 + r1) * 320L + g1 * 8;

#define HSTAGE(KB) { \
    GLOAD16(gA0 + (KB) * 32, &As3[(KB) % 3][wf_u * 512]); \
    GLOAD16(gA1 + (KB) * 32, &As3[(KB) % 3][2048 + wf_u * 512]); }

    HSTAGE(0); HSTAGE(1);

    f32x4 acc[2][5];
    #pragma unroll
    for (int i = 0; i < 2; ++i)
        #pragma unroll
        for (int j = 0; j < 5; ++j) acc[i][j] = (f32x4)(0.f);
    const int ar0 = (wf * 32 + tl) * 32 + (thi ^ ((tl >> 1) & 3)) * 8;
    const int br0 = tl * 328 + thi * 8;

#define HSTEP(KB, VN) { \
    asm volatile("s_waitcnt vmcnt(" #VN ")" ::: "memory"); \
    __builtin_amdgcn_s_barrier(); \
    __builtin_amdgcn_sched_barrier(0); \
    if ((KB) + 2 < 10) HSTAGE((KB) + 2); \
    TCOMP(KB, (&As3[(KB) % 3][0])); }

    HSTEP(0, 2) HSTEP(1, 2) HSTEP(2, 2) HSTEP(3, 2) HSTEP(4, 2)
    HSTEP(5, 2) HSTEP(6, 2) HSTEP(7, 2) HSTEP(8, 2) HSTEP(9, 0)
#undef HSTEP
#undef HSTAGE

    // epilogue: rows e = m0 + wf*32 + fr*16 + tl; HG[e^1] = shfl_xor(acc,1)
    #pragma unroll
    for (int fr = 0; fr < 2; ++fr) {
        const long row = m0 + wf * 32 + fr * 16 + tl;
        const int srow = srcidx[row];
        #pragma unroll
        for (int fc = 0; fc < 5; ++fc) {
            const int c0 = n0 + fc * 16 + thi * 4;
            float o0 = __shfl_xor(acc[fr][fc][0], 1, 64);
            float o1 = __shfl_xor(acc[fr][fc][1], 1, 64);
            float o2 = __shfl_xor(acc[fr][fc][2], 1, 64);
            float o3 = __shfl_xor(acc[fr][fc][3], 1, 64);
            const ushort4 fg = *(const ushort4*)&FG[(long)srow * 320 + c0];
            const ushort4 xv = *(const ushort4*)&hx[row * 320 + c0];
            float v0 = b2f(fg.x) + b2f(xv.x) - o0;
            float v1 = b2f(fg.y) + b2f(xv.y) - o1;
            float v2 = b2f(fg.z) + b2f(xv.z) - o2;
            float v3 = b2f(fg.w) + b2f(xv.w) - o3;
            if (c0 < 300) {
                const float4 bs = *(const float4*)&bias[c0];
                v0 += bs.x; v1 += bs.y; v2 += bs.z; v3 += bs.w;
            }
            v0 = fmaxf(v0, 0.f); v1 = fmaxf(v1, 0.f);
            v2 = fmaxf(v2, 0.f); v3 = fmaxf(v3, 0.f);
            uint2 p;
            p.x = (u32)f2b(v0) | ((u32)f2b(v1) << 16);
            p.y = (u32)f2b(v2) | ((u32)f2b(v3) << 16);
            *(uint2*)&outB[row * 320 + c0] = p;
        }
    }
}

// ---------------- wide GEMM (K=1600, phased): fhb = wideA @ Ucat + bvo ----------------
// 5 phases; per phase: stage B quarter-phase (52.5KB) once, then 10 ESTEP chunks over A.
__global__ __launch_bounds__(256, 2) void wgemm_k(
    const u16* __restrict__ A /*wideA, stride 1600*/, const u16* __restrict__ Bp /*[q][ph][80][328]*/,
    const float* __restrict__ bias /*bvoF[320]*/, u16* __restrict__ outB /*fhb*/)
{
    __shared__ __attribute__((aligned(16))) u16 Bs[80 * 328];
    __shared__ __attribute__((aligned(16))) u16 As3[3][128 * 32];
    const int tid = threadIdx.x;
    const int wf = tid >> 6, lane = tid & 63;
    const int tl = lane & 15, thi = lane >> 4;
    const int bid = blockIdx.x;
    const int gid = (bid & 7) * ((int)gridDim.x >> 3) + (bid >> 3);
    const long m0 = (long)(gid >> 2) * 128;
    const int q = gid & 3;
    const int n0 = q * 80;
    const int wf_u = __builtin_amdgcn_readfirstlane(wf);
    const u16* BsrcQ = Bp + (long)q * (5 * BQ_U16);

    const int r1 = tid >> 2;
    const int g1 = (tid & 3) ^ ((r1 >> 1) & 3);
    const u16* gA0 = A + (m0 + r1) * 1600L + g1 * 8;
    const u16* gA1 = A + (m0 + 64 + r1) * 1600L + g1 * 8;

    f32x4 acc[2][5];
    #pragma unroll
    for (int i = 0; i < 2; ++i)
        #pragma unroll
        for (int j = 0; j < 5; ++j) acc[i][j] = (f32x4)(0.f);
    const int ar0 = (wf * 32 + tl) * 32 + (thi ^ ((tl >> 1) & 3)) * 8;
    const int br0 = tl * 328 + thi * 8;

    #pragma unroll
    for (int ph = 0; ph < 5; ++ph) {
        if (ph) __syncthreads();               // all waves done reading Bs/As3 of prev phase
        const u16* Bsrc = BsrcQ + ph * BQ_U16;
        #pragma unroll
        for (int i = 0; i < 13; ++i) {
            int t = i * 256 + tid;
            if (t < 3280)
                GLOAD16(Bsrc + (long)t * 8, &Bs[(i * 256 + wf_u * 64) * 8]);
        }
        const long ko = (long)ph * 320;

#define WSTAGE(KB) { \
    GLOAD16(gA0 + ko + (KB) * 32, &As3[(KB) % 3][wf_u * 512]); \
    GLOAD16(gA1 + ko + (KB) * 32, &As3[(KB) % 3][2048 + wf_u * 512]); }

        WSTAGE(0); WSTAGE(1);

#define WSTEP(KB, VN) { \
    asm volatile("s_waitcnt vmcnt(" #VN ")" ::: "memory"); \
    __builtin_amdgcn_s_barrier(); \
    __builtin_amdgcn_sched_barrier(0); \
    if ((KB) + 2 < 10) WSTAGE((KB) + 2); \
    TCOMP(KB, (&As3[(KB) % 3][0])); }

        WSTEP(0, 2) WSTEP(1, 2) WSTEP(2, 2) WSTEP(3, 2) WSTEP(4, 2)
        WSTEP(5, 2) WSTEP(6, 2) WSTEP(7, 2) WSTEP(8, 2) WSTEP(9, 0)
#undef WSTEP
#undef WSTAGE
    }

    #pragma unroll
    for (int fr = 0; fr < 2; ++fr) {
        const long row = m0 + wf * 32 + fr * 16 + tl;
        #pragma unroll
        for (int fc = 0; fc < 5; ++fc) {
            const int c0 = n0 + fc * 16 + thi * 4;
            f32x4 v = acc[fr][fc];
            const float4 bs = *(const float4*)&bias[c0];
            v[0] += bs.x; v[1] += bs.y; v[2] += bs.z; v[3] += bs.w;
            uint2 p;
            p.x = (u32)f2b(v[0]) | ((u32)f2b(v[1]) << 16);
            p.y = (u32)f2b(v[2]) | ((u32)f2b(v[3]) << 16);
            *(uint2*)&outB[row * 320 + c0] = p;
        }
    }
}

// ---------------- fused attention on raw h ----------------
__global__ __launch_bounds__(256) void attn2_k(
    const u16* __restrict__ qg, const u16* __restrict__ hcur,
    const int* __restrict__ mail, u16* __restrict__ wideA)
{
    const int tid = threadIdx.x;
    const long n = (long)blockIdx.x * 4 + (tid >> 6);
    const int lane = tid & 63;
    const bool act = lane < 40;
    const int ll = act ? lane : 39;

    int idx[8];
    #pragma unroll
    for (int j = 0; j < 8; ++j) idx[j] = mail[n * 8 + j];
    uint4 hr[8];
    #pragma unroll
    for (int j = 0; j < 8; ++j)
        hr[j] = *(const uint4*)&hcur[(long)idx[j] * 320 + ll * 8];
    uint4 qv[4];
    #pragma unroll
    for (int h = 0; h < 4; ++h)
        qv[h] = *(const uint4*)&qg[n * 1280 + h * 320 + ll * 8];
    if (!act) {
        #pragma unroll
        for (int j = 0; j < 8; ++j) hr[j] = make_uint4(0, 0, 0, 0);
    }

    float qf[4][8];
    #pragma unroll
    for (int h = 0; h < 4; ++h) {
        const u32 w[4] = {qv[h].x, qv[h].y, qv[h].z, qv[h].w};
        #pragma unroll
        for (int p = 0; p < 4; ++p) {
            qf[h][2 * p]     = b2f((u16)(w[p] & 0xFFFF));
            qf[h][2 * p + 1] = b2f((u16)(w[p] >> 16));
        }
    }

    float s[4][8];
    #pragma unroll
    for (int j = 0; j < 8; ++j) {
        float hf[8];
        const u32 w[4] = {hr[j].x, hr[j].y, hr[j].z, hr[j].w};
        #pragma unroll
        for (int p = 0; p < 4; ++p) {
            hf[2 * p]     = b2f((u16)(w[p] & 0xFFFF));
            hf[2 * p + 1] = b2f((u16)(w[p] >> 16));
        }
        #pragma unroll
        for (int h = 0; h < 4; ++h) {
            float d = 0.f;
            #pragma unroll
            for (int m = 0; m < 8; ++m) d += qf[h][m] * hf[m];
            d += __shfl_xor(d, 32, 64);
            d += __shfl_xor(d, 16, 64);
            d += __shfl_xor(d, 8, 64);
            d += __shfl_xor(d, 4, 64);
            d += __shfl_xor(d, 2, 64);
            d += __shfl_xor(d, 1, 64);
            s[h][j] = d;
        }
    }

    float p_[4][8];
    #pragma unroll
    for (int h = 0; h < 4; ++h) {
        float mx = s[h][0];
        #pragma unroll
        for (int j = 1; j < 8; ++j) mx = fmaxf(mx, s[h][j]);
        float sum = 0.f;
        #pragma unroll
        for (int j = 0; j < 8; ++j) { p_[h][j] = __expf(s[h][j] - mx); sum += p_[h][j]; }
        const float inv = 1.f / sum;
        #pragma unroll
        for (int j = 0; j < 8; ++j) p_[h][j] *= inv;
    }

    float y[4][8];
    #pragma unroll
    for (int h = 0; h < 4; ++h)
        #pragma unroll
        for (int m = 0; m < 8; ++m) y[h][m] = 0.f;
    #pragma unroll
    for (int j = 0; j < 8; ++j) {
        float hf[8];
        const u32 w[4] = {hr[j].x, hr[j].y, hr[j].z, hr[j].w};
        #pragma unroll
        for (int p = 0; p < 4; ++p) {
            hf[2 * p]     = b2f((u16)(w[p] & 0xFFFF));
            hf[2 * p + 1] = b2f((u16)(w[p] >> 16));
        }
        #pragma unroll
        for (int h = 0; h < 4; ++h)
            #pragma unroll
            for (int m = 0; m < 8; ++m) y[h][m] += p_[h][j] * hf[m];
    }
    if (act) {
        #pragma unroll
        for (int h = 0; h < 4; ++h) {
            uint4 o;
            o.x = (u32)f2b(y[h][0]) | ((u32)f2b(y[h][1]) << 16);
            o.y = (u32)f2b(y[h][2]) | ((u32)f2b(y[h][3]) << 16);
            o.z = (u32)f2b(y[h][4]) | ((u32)f2b(y[h][5]) << 16);
            o.w = (u32)f2b(y[h][6]) | ((u32)f2b(y[h][7]) << 16);
            *(uint4*)&wideA[n * 1600 + h * 320 + lane * 8] = o;
        }
    }
}

// ---------------- generic GEMM (64-row tiles) — final 960-K projection only ----------------
#define LOADB(bq, kt1) { const long ko_ = (long)(kt1) << 6; \
    _Pragma("unroll") for (int fc = 0; fc < 5; ++fc) \
      _Pragma("unroll") for (int ks = 0; ks < 2; ++ks) \
        bq[fc][ks] = *(const bf16x8*)(gBw + (long)fc * 16 * KP + ko_ + ks * 32); }

#define READA(lkt) { \
    _Pragma("unroll") for (int fr = 0; fr < 4; ++fr) \
      _Pragma("unroll") for (int ks = 0; ks < 2; ++ks) \
        a[fr][ks] = *(const bf16x8*)&As[(fr * 16 + tl) * 320 + ((((lkt) * 8 + ks * 4 + thi) ^ sx) * 8)]; }

#define DOMFMA(bq) { _Pragma("unroll") for (int fr = 0; fr < 4; ++fr) \
    _Pragma("unroll") for (int fc = 0; fc < 5; ++fc) \
      _Pragma("unroll") for (int ks = 0; ks < 2; ++ks) \
        acc[fr][fc] = __builtin_amdgcn_mfma_f32_16x16x32_bf16(bq[fc][ks], a[fr][ks], acc[fr][fc], 0, 0, 0); }

template<int KP>
__global__ __launch_bounds__(256, 2) void gemm_k(
    const u16* __restrict__ A,
    const u16* __restrict__ BT,
    const float* __restrict__ bias,
    float* __restrict__ outF, int ostride, int ocols)
{
    __shared__ u16 As[64 * 320];
    const int tid = threadIdx.x;
    const int w = tid >> 6, lane = tid & 63;
    const int tl = lane & 15, thi = lane >> 4;
    const int sx = tl & 7;
    const long m0 = (long)blockIdx.x * 64;
    const int w_u = __builtin_amdgcn_readfirstlane(w);

    const u16* gBw = BT + ((long)(w * 80 + tl)) * KP + thi * 8;

    f32x4 acc[4][5];
    #pragma unroll
    for (int i = 0; i < 4; ++i)
        #pragma unroll
        for (int j = 0; j < 5; ++j) acc[i][j] = (f32x4)(0.f);

    constexpr int NCH = KP / 320;
    constexpr int NST = KP >> 6;
    bf16x8 bA[5][2], bB[5][2], a[4][2];

    #pragma unroll
    for (int kb = 0; kb < NCH; ++kb) {
        if (kb) __syncthreads();
        #pragma unroll
        for (int i = 0; i < 10; ++i) {
            const int c = i * 256 + w_u * 64 + lane;
            const int r = c / 40, s = c - r * 40;
            GLOAD16(A + (m0 + r) * (long)KP + kb * 320 + ((s ^ (r & 7)) * 8),
                    &As[(i * 256 + w_u * 64) * 8]);
        }
        if (kb == 0) LOADB(bA, 0);
        __syncthreads();
        #pragma unroll
        for (int lkt = 0; lkt < 5; ++lkt) {
            const int kt = kb * 5 + lkt;
            if (kt + 1 < NST) {
                if (kt & 1) { LOADB(bA, kt + 1); } else { LOADB(bB, kt + 1); }
            }
            READA(lkt);
            if (kt & 1) { DOMFMA(bB); } else { DOMFMA(bA); }
        }
    }

    #pragma unroll
    for (int fr = 0; fr < 4; ++fr) {
        const long row = m0 + fr * 16 + tl;
        #pragma unroll
        for (int fc = 0; fc < 5; ++fc) {
            const int c0 = w * 80 + fc * 16 + thi * 4;
            f32x4 v = acc[fr][fc];
            if (bias && c0 < 300) {
                const float4 bs = *(const float4*)&bias[c0];
                v[0] += bs.x; v[1] += bs.y; v[2] += bs.z; v[3] += bs.w;
            }
            if (c0 < ocols)
                *(float4*)&outF[row * (long)ostride + c0] = make_float4(v[0], v[1], v[2], v[3]);
        }
    }
}

// ---------------- build concat A = [mail_sum | f_h | f] (bf16, N x 960) ----------------
__global__ __launch_bounds__(256) void concat_k(
    const u16* __restrict__ hb, const u16* __restrict__ fhb,
    const float* __restrict__ f, const int* __restrict__ mail,
    u16* __restrict__ Acat)
{
    const long n = blockIdx.x;
    int m[8];
    #pragma unroll
    for (int j = 0; j < 8; ++j) m[j] = mail[n * 8 + j];
    for (int c = threadIdx.x; c < 960; c += 256) {
        float v;
        if (c < 300) {
            float s = 0.f;
            #pragma unroll
            for (int j = 0; j < 8; ++j) s += b2f(hb[(long)m[j] * 320 + c]);
            v = s;
        } else if (c < 600) v = b2f(fhb[n * 320 + (c - 300)]);
        else if (c < 900) v = f[n * 300 + (c - 600)];
        else v = 0.f;
        Acat[n * 960 + c] = f2b(v);
    }
}

extern "C" void kernel_launch(void* const* d_in, const int* in_sizes, int n_in,
                              void* d_out, int out_size, void* d_ws, size_t ws_size,
                              hipStream_t stream)
{
    const int N = N_NODES, E = E_EDGES;
    const float* f    = (const float*)d_in[0];
    const float* x    = (const float*)d_in[1];
    const int*   mail = (const int*)d_in[2];
    const int*   srcx = (const int*)d_in[3];
    const float* Wq = (const float*)d_in[4];   const float* bq = (const float*)d_in[5];
    const float* Wk = (const float*)d_in[6];   /* bk unused (softmax-invariant) */
    const float* Wv = (const float*)d_in[8];   const float* bv = (const float*)d_in[9];
    const float* Wo = (const float*)d_in[10];  const float* bo = (const float*)d_in[11];
    const float* Wmp = (const float*)d_in[12]; const float* bmp = (const float*)d_in[13];
    const float* Wlast = (const float*)d_in[14]; const float* blast = (const float*)d_in[15];
    float* out = (float*)d_out;

    char* ws = (char*)d_ws;
    size_t off = 0;
    auto alloc = [&](size_t b) -> void* {
        void* p = ws + off; off += (b + 255) & ~(size_t)255; return p;
    };
    u16* hb    = (u16*)alloc((size_t)E * 320 * 2);   // bf16(x); final h after iter 1
    u16* hb2   = (u16*)alloc((size_t)E * 320 * 2);   // h after iter 0
    u16* qgb   = (u16*)alloc((size_t)N * 1280 * 2);  // qg
    u16* wideA = (u16*)alloc((size_t)N * 1600 * 2);  // [Ycat(1280) | feat(320)]
    u16* fhb   = (u16*)alloc((size_t)N * 320 * 2);
    u16* FGb   = (u16*)alloc((size_t)N * 320 * 2);   // FG = fhb @ Wmp
    u16* Acat  = (u16*)alloc((size_t)N * 960 * 2);
    u16* WqkS  = (u16*)alloc((size_t)16 * BQ_U16 * 2);
    u16* Wm0S  = (u16*)alloc((size_t)4 * BQ_U16 * 2);
    u16* Wm1S  = (u16*)alloc((size_t)4 * BQ_U16 * 2);
    u16* UcatP = (u16*)alloc((size_t)4 * 5 * BQ_U16 * 2);
    u16* WcatB = (u16*)alloc((size_t)960 * 320 * 2);
    float* bqkF = (float*)alloc(1280 * 4);
    float* bvoF = (float*)alloc(320 * 4);

    // ---- weight preprocessing ----
    {
        wqkq_k<<<(16 * BQ_U16 + 255) / 256, 256, 0, stream>>>(Wq, Wk, WqkS);
        bqk_k<<<5, 256, 0, stream>>>(bq, Wk, bqkF);
        ucatp_k<<<(int)((4L * 5 * BQ_U16 + 255) / 256), 256, 0, stream>>>(Wv, Wo, UcatP);
        bvo_k<<<2, 256, 0, stream>>>(bv, Wo, bo, bvoF);
        int blks = (4 * BQ_U16 + 255) / 256;
        convTq_k<<<blks, 256, 0, stream>>>(Wmp, Wm0S);
        convTq_k<<<blks, 256, 0, stream>>>(Wmp + 90000, Wm1S);
        long totc = (long)320 * 960;
        convT_k<<<(int)((totc + 255) / 256), 256, 0, stream>>>(Wlast, 900, 300, WcatB, 960, totc);
    }
    // ---- activations ----
    {
        long totE = (long)E * 40;
        padconv_k<<<(int)((totE + 255) / 256), 256, 0, stream>>>(x, 300, hb, 320, nullptr, 0, totE);
        long totN = (long)N * 40;
        padconv_k<<<(int)((totN + 255) / 256), 256, 0, stream>>>(f, 300, fhb, 320, wideA + 1280, 1600, totN);
    }

    const int GQG = (N / 128) * 16;  // 4096 (%8==0)
    const int GNQ = (N / 128) * 4;   // 1024 (%8==0)
    const int GEH = (E / 128) * 4;   // 8192 (%8==0)

    for (int it = 0; it < 2; ++it) {
        const float* bmpi = bmp + it * 300;
        const u16* WmS = it ? Wm1S : Wm0S;
        const u16* hcur = it ? hb2 : hb;
        u16* hnxt = it ? hb : hb2;
        // qg = f_h @ Wqk + bqk
        ngemm_k<4, 1280><<<GQG, 256, 0, stream>>>(fhb, WqkS, bqkF, qgb);
        // attention on raw h -> wideA[:,0:1280]
        attn2_k<<<N / 4, 256, 0, stream>>>(qgb, hcur, mail, wideA);
        // f_h' = [Ycat | feat] @ Ucat + bvo   (phased K=1600)
        wgemm_k<<<GNQ, 256, 0, stream>>>(wideA, UcatP, bvoF, fhb);
        // feat slot refresh for next iteration
        featcopy_k<<<(int)(((long)N * 40 + 255) / 256), 256, 0, stream>>>(fhb, wideA);
        // FG = f_h' @ Wmp (no bias)
        ngemm_k<2, 320><<<GNQ, 256, 0, stream>>>(fhb, WmS, nullptr, FGb);
        // h' = relu(x + FG[src] - (hcur@Wmp)[e^1] + bmp)  — dense GEMM + epilogue swap
        hgemm_k<<<GEH, 256, 0, stream>>>(hcur, WmS, FGb, hb, srcx, bmpi, hnxt);
    }

    // Acat = [mail_sum | f_h | f]
    concat_k<<<N, 256, 0, stream>>>(hb, fhb, f, mail, Acat);
    // out = Acat @ Wlast + blast
    gemm_k<960><<<N / 64, 256, 0, stream>>>(Acat, WcatB, blast, out, 300, 300);
}

// Round 14
// 1336.681 us; speedup vs baseline: 1.0439x; 1.0439x over previous
//
#include <hip/hip_runtime.h>

typedef unsigned short u16;
typedef unsigned int u32;
typedef __bf16 bf16x8 __attribute__((ext_vector_type(8)));
typedef float f32x4 __attribute__((ext_vector_type(4)));

#define N_NODES 32768
#define E_EDGES 262144
#define BQ_U16 26240    // one 80-col quarter of padded B: 80*328 u16 (52.5 KB)
#define S75 0.11547005383792515f

__device__ __forceinline__ float b2f(u16 u) {
    union { u32 u; float f; } x; x.u = ((u32)u) << 16; return x.f;
}
__device__ __forceinline__ u16 f2b(float f) {
    union { float f; u32 u; } x; x.f = f;
    u32 r = x.u + 0x7FFF + ((x.u >> 16) & 1);
    return (u16)(r >> 16);
}

#define GLOAD16(g, l) \
    __builtin_amdgcn_global_load_lds((const __attribute__((address_space(1))) u32*)(g), \
                                     (__attribute__((address_space(3))) u32*)(l), 16, 0, 0)

// ---------------- plain weight transpose (final 960-K projection) ----------------
__global__ void convT_k(const float* __restrict__ src, int R, int C,
                        u16* __restrict__ dst, int KP_, long total) {
    long id = (long)blockIdx.x * blockDim.x + threadIdx.x;
    if (id >= total) return;
    int n = (int)(id / KP_), k = (int)(id % KP_);
    dst[id] = (k < R && n < C) ? f2b(src[(long)k * C + n]) : (u16)0;
}

// ---------------- quarter-weight build: dst[q][r][c], c in [0,328) = W[c][q*80+r] ----------------
__global__ void convTq_k(const float* __restrict__ src, u16* __restrict__ dst) {
    int id = blockIdx.x * 256 + threadIdx.x;
    if (id >= 4 * BQ_U16) return;
    int q = id / BQ_U16, rem = id % BQ_U16;
    int r = rem / 328, c = rem % 328;
    int n = q * 80 + r;
    dst[id] = (c < 300 && n < 300) ? f2b(src[(long)c * 300 + n]) : (u16)0;
}

// ---------------- Wqk build (16 quarters of 80 cols, 328-padded K) ----------------
__global__ void wqkq_k(const float* __restrict__ Wq, const float* __restrict__ Wk,
                       u16* __restrict__ dst) {
    int id = blockIdx.x * 256 + threadIdx.x;
    if (id >= 16 * BQ_U16) return;
    int q = id / BQ_U16, rem = id % BQ_U16;
    int r = rem / 328, c = rem % 328;
    int h = q >> 2;
    int cc = (q & 3) * 80 + r;
    float acc = 0.f;
    if (c < 300 && cc < 300) {
        const float* wq = Wq + (long)c * 300 + 75 * h;
        const float* wk = Wk + (long)cc * 300 + 75 * h;
        for (int d = 0; d < 75; ++d) acc += wq[d] * wk[d];
        acc *= S75;
    }
    dst[id] = f2b(acc);
}

// bqk[320h+cc] = S75 * sum_d bq[75h+d]*Wk[cc,75h+d]
__global__ void bqk_k(const float* __restrict__ bq, const float* __restrict__ Wk,
                      float* __restrict__ dst) {
    int n = blockIdx.x * 256 + threadIdx.x;
    if (n >= 1280) return;
    int h = n / 320, cc = n % 320;
    float acc = 0.f;
    if (cc < 300) {
        const float* b = bq + 75 * h;
        const float* wk = Wk + (long)cc * 300 + 75 * h;
        for (int d = 0; d < 75; ++d) acc += b[d] * wk[d];
        acc *= S75;
    }
    dst[n] = acc;
}

// ---------------- phased Ucat build: dst[q][ph][r<80][c<328]; k = ph*320+c, n = q*80+r ----------------
__global__ void ucatp_k(const float* __restrict__ Wv, const float* __restrict__ Wo,
                        u16* __restrict__ dst) {
    long id = (long)blockIdx.x * 256 + threadIdx.x;
    if (id >= 4L * 5 * BQ_U16) return;
    int q = (int)(id / (5 * BQ_U16));
    int rem = (int)(id % (5 * BQ_U16));
    int ph = rem / BQ_U16;
    int rem2 = rem % BQ_U16;
    int r = rem2 / 328, c = rem2 % 328;
    int n = q * 80 + r;
    float acc = 0.f;
    if (n < 300 && c < 320) {
        if (ph < 4) {
            int a = c;
            if (a < 300) {
                const float* wv = Wv + (long)a * 300 + 75 * ph;
                const float* wo = Wo + (long)(75 * ph) * 300 + n;
                for (int d = 0; d < 75; ++d) acc += wv[d] * wo[(long)d * 300];
            }
        } else {
            int a = c;
            if (a < 300) {
                const float* wv = Wv + (long)a * 300;
                const float* wo = Wo + n;
                for (int d = 0; d < 300; ++d) acc += wv[d] * wo[(long)d * 300];
            }
        }
    }
    dst[id] = f2b(acc);
}

// bvo[n] = sum_d bv[d]*Wo[d,n] + bo[n]
__global__ void bvo_k(const float* __restrict__ bv, const float* __restrict__ Wo,
                      const float* __restrict__ bo, float* __restrict__ dst) {
    int n = blockIdx.x * 256 + threadIdx.x;
    if (n >= 320) return;
    float acc = 0.f;
    if (n < 300) {
        for (int d = 0; d < 300; ++d) acc += bv[d] * Wo[(long)d * 300 + n];
        acc += bo[n];
    }
    dst[n] = acc;
}

// ---------------- activation pad+convert ----------------
__global__ void padconv_k(const float* __restrict__ src, int C,
                          u16* __restrict__ dst, int CP,
                          u16* __restrict__ dst2, int CP2, long total) {
    long id = (long)blockIdx.x * blockDim.x + threadIdx.x;
    if (id >= total) return;
    int cw = CP >> 3;
    long row = id / cw;
    int c8 = (int)(id % cw) * 8;
    u32 w[4];
    #pragma unroll
    for (int p = 0; p < 4; ++p) {
        int c0 = c8 + 2 * p, c1 = c0 + 1;
        u16 lo = (c0 < C) ? f2b(src[row * C + c0]) : (u16)0;
        u16 hi = (c1 < C) ? f2b(src[row * C + c1]) : (u16)0;
        w[p] = (u32)lo | ((u32)hi << 16);
    }
    u32* d = (u32*)(dst + row * CP + c8);
    d[0] = w[0]; d[1] = w[1]; d[2] = w[2]; d[3] = w[3];
    if (dst2) {
        u32* d2 = (u32*)(dst2 + row * CP2 + c8);
        d2[0] = w[0]; d2[1] = w[1]; d2[2] = w[2]; d2[3] = w[3];
    }
}

// ---------------- feat copy: wideA[n][1280+c] = fhb[n][c] ----------------
__global__ void featcopy_k(const u16* __restrict__ src, u16* __restrict__ dst) {
    long id = (long)blockIdx.x * 256 + threadIdx.x;
    if (id >= (long)N_NODES * 40) return;
    long row = id / 40;
    int c8 = (int)(id % 40) * 8;
    *(uint4*)&dst[row * 1600 + 1280 + c8] = *(const uint4*)&src[row * 320 + c8];
}

// ==================== 16-wave barrier-free GEMM core ====================
// block = 1024 thr (16 waves) x (512 rows x 80 cols). B quarter staged once (1 barrier,
// uniform 4 gloads/thread incl. clamped tail + dump). Each wave owns 32 rows with a
// PRIVATE 3-buffer gload_lds pipeline, per-wave counted vmcnt — ZERO K-loop barriers.
// 149 KB LDS -> 1 block/CU, 16 waves = 4 waves/SIMD.

#define GEMM16_SHARED \
    __shared__ __attribute__((aligned(16))) u16 Bs[3328 * 8];     /* 53.25 KB */ \
    __shared__ __attribute__((aligned(16))) u16 dumpB[512];       /* 1 KB */ \
    __shared__ __attribute__((aligned(16))) u16 As3[3][512 * 32]; /* 96 KB */

#define GEMM16_PRE(QBITS, LDA) \
    const int tid = threadIdx.x; \
    const int w = tid >> 6, lane = tid & 63; \
    const int tl = lane & 15, thi = lane >> 4; \
    const int bid = blockIdx.x; \
    const int gid = (bid & 7) * ((int)gridDim.x >> 3) + (bid >> 3); \
    const long m0 = (long)(gid >> (QBITS)) * 512; \
    const int q = gid & ((1 << (QBITS)) - 1); \
    const int n0 = q * 80; \
    const int w_u = __builtin_amdgcn_readfirstlane(w); \
    const u16* Bsrc = Bswz + q * BQ_U16; \
    /* B prologue: 4 uniform gloads per thread */ \
    _Pragma("unroll") \
    for (int i = 0; i < 3; ++i) \
        GLOAD16(Bsrc + (long)(i * 1024 + tid) * 8, &Bs[(i * 1024 + w_u * 64) * 8]); \
    { \
        int t = 3072 + tid; \
        int ts = t < 3280 ? t : 3279; \
        u16* bdst = (w_u < 4) ? &Bs[(3072 + w_u * 64) * 8] : dumpB; \
        GLOAD16(Bsrc + (long)ts * 8, bdst); \
    } \
    __builtin_amdgcn_sched_barrier(0); \
    /* per-wave A staging geometry: wave owns rows m0+32w .. +31 */ \
    const int rr = lane >> 2;                 /* 0..15 */ \
    const int gsrc = (lane & 3) ^ (rr & 3);   /* inverse-swizzled 16B slot */ \
    const u16* pA0 = A + (m0 + w * 32 + rr) * (long)(LDA) + gsrc * 8; \
    const u16* pA1 = pA0 + 16L * (LDA); \
    u16* awbase = &As3[0][0];

#define ASTAGE16(KB) { \
    u16* d_ = &As3[(KB) % 3][w_u * 1024]; \
    GLOAD16(pA0 + (KB) * 32, d_); \
    GLOAD16(pA1 + (KB) * 32, d_ + 512); }

#define TCOMP16(KB) { \
    const u16* aw_ = &As3[(KB) % 3][w * 1024]; \
    bf16x8 a0_ = *(const bf16x8*)&aw_[tl * 32 + (thi ^ (tl & 3)) * 8]; \
    bf16x8 a1_ = *(const bf16x8*)&aw_[512 + tl * 32 + (thi ^ (tl & 3)) * 8]; \
    __builtin_amdgcn_s_setprio(1); \
    _Pragma("unroll") for (int fc = 0; fc < 5; ++fc) { \
        bf16x8 bb_ = *(const bf16x8*)&Bs[tl * 328 + thi * 8 + fc * 5248 + (KB) * 32]; \
        acc[0][fc] = __builtin_amdgcn_mfma_f32_16x16x32_bf16(bb_, a0_, acc[0][fc], 0, 0, 0); \
        acc[1][fc] = __builtin_amdgcn_mfma_f32_16x16x32_bf16(bb_, a1_, acc[1][fc], 0, 0, 0); } \
    __builtin_amdgcn_s_setprio(0); }

#define GEMM16_LOOP \
    ASTAGE16(0); ASTAGE16(1); ASTAGE16(2); \
    f32x4 acc[2][5]; \
    _Pragma("unroll") for (int i = 0; i < 2; ++i) \
        _Pragma("unroll") for (int j = 0; j < 5; ++j) acc[i][j] = (f32x4)(0.f); \
    asm volatile("s_waitcnt vmcnt(6)" ::: "memory");   /* own B gloads done */ \
    __builtin_amdgcn_s_barrier();                      /* all waves' B done */ \
    __builtin_amdgcn_sched_barrier(0); \
    /* KB = 0..9: wave-private pipeline, no barriers */ \
    _Pragma("unroll") \
    for (int KB = 0; KB < 10; ++KB) { \
        if (KB <= 7)      { asm volatile("s_waitcnt vmcnt(4)" ::: "memory"); } \
        else if (KB == 8) { asm volatile("s_waitcnt vmcnt(2)" ::: "memory"); } \
        else              { asm volatile("s_waitcnt vmcnt(0)" ::: "memory"); } \
        __builtin_amdgcn_sched_barrier(0); \
        TCOMP16(KB); \
        asm volatile("s_waitcnt lgkmcnt(0)" ::: "memory");  /* reads done before buf reuse */ \
        __builtin_amdgcn_sched_barrier(0); \
        if (KB + 3 < 10) ASTAGE16(KB + 3); \
    } \
    (void)awbase;

// ---------------- N-scale GEMM: out(M x OSTR) = A(M x 320) @ Bq (+bias), bf16 out ----------------
template<int QBITS, int OSTR>
__global__ __launch_bounds__(1024, 4) void ngemm16_k(
    const u16* __restrict__ A, const u16* __restrict__ Bswz,
    const float* __restrict__ bias, u16* __restrict__ outB)
{
    GEMM16_SHARED
    GEMM16_PRE(QBITS, 320)
    GEMM16_LOOP

    #pragma unroll
    for (int fr = 0; fr < 2; ++fr) {
        const long row = m0 + w * 32 + fr * 16 + tl;
        #pragma unroll
        for (int fc = 0; fc < 5; ++fc) {
            const int c0 = n0 + fc * 16 + thi * 4;
            f32x4 v = acc[fr][fc];
            if (bias) {
                const float4 bs = *(const float4*)&bias[c0];
                v[0] += bs.x; v[1] += bs.y; v[2] += bs.z; v[3] += bs.w;
            }
            uint2 p;
            p.x = (u32)f2b(v[0]) | ((u32)f2b(v[1]) << 16);
            p.y = (u32)f2b(v[2]) | ((u32)f2b(v[3]) << 16);
            *(uint2*)&outB[row * (long)OSTR + c0] = p;
        }
    }
}

// ---------------- h-update: HG = hcur @ Wm (dense); epilogue gather+pair-swap ----------------
// h'[e] = relu(x[e] + FG[src[e]] - HG[e^1] + bmp); HG[e^1] via shfl_xor(acc,1).
__global__ __launch_bounds__(1024, 4) void hgemm16_k(
    const u16* __restrict__ A /*hcur*/, const u16* __restrict__ Bswz /*Wm quarters*/,
    const u16* __restrict__ FG, const u16* __restrict__ hx,
    const int* __restrict__ srcidx, const float* __restrict__ bias,
    u16* __restrict__ outB)
{
    GEMM16_SHARED
    GEMM16_PRE(2, 320)
    GEMM16_LOOP

    #pragma unroll
    for (int fr = 0; fr < 2; ++fr) {
        const long row = m0 + w * 32 + fr * 16 + tl;
        const int srow = srcidx[row];
        #pragma unroll
        for (int fc = 0; fc < 5; ++fc) {
            const int c0 = n0 + fc * 16 + thi * 4;
            float o0 = __shfl_xor(acc[fr][fc][0], 1, 64);
            float o1 = __shfl_xor(acc[fr][fc][1], 1, 64);
            float o2 = __shfl_xor(acc[fr][fc][2], 1, 64);
            float o3 = __shfl_xor(acc[fr][fc][3], 1, 64);
            const ushort4 fg = *(const ushort4*)&FG[(long)srow * 320 + c0];
            const ushort4 xv = *(const ushort4*)&hx[row * 320 + c0];
            float v0 = b2f(fg.x) + b2f(xv.x) - o0;
            float v1 = b2f(fg.y) + b2f(xv.y) - o1;
            float v2 = b2f(fg.z) + b2f(xv.z) - o2;
            float v3 = b2f(fg.w) + b2f(xv.w) - o3;
            if (c0 < 300) {
                const float4 bs = *(const float4*)&bias[c0];
                v0 += bs.x; v1 += bs.y; v2 += bs.z; v3 += bs.w;
            }
            v0 = fmaxf(v0, 0.f); v1 = fmaxf(v1, 0.f);
            v2 = fmaxf(v2, 0.f); v3 = fmaxf(v3, 0.f);
            uint2 p;
            p.x = (u32)f2b(v0) | ((u32)f2b(v1) << 16);
            p.y = (u32)f2b(v2) | ((u32)f2b(v3) << 16);
            *(uint2*)&outB[row * 320 + c0] = p;
        }
    }
}

// ================== 4-wave tile compute macro (wgemm): acc[2][5] ==================
#define TCOMP(KB, APTR) do { \
    bf16x8 av_[2], bb_[5]; \
    _Pragma("unroll") for (int fr = 0; fr < 2; ++fr) \
        av_[fr] = *(const bf16x8*)&(APTR)[ar0 + fr * 512]; \
    _Pragma("unroll") for (int fc = 0; fc < 5; ++fc) \
        bb_[fc] = *(const bf16x8*)&Bsw[br0 + fc * 5248 + (KB) * 32]; \
    __builtin_amdgcn_s_setprio(1); \
    _Pragma("unroll") for (int fr = 0; fr < 2; ++fr) \
        _Pragma("unroll") for (int fc = 0; fc < 5; ++fc) \
            acc[fr][fc] = __builtin_amdgcn_mfma_f32_16x16x32_bf16(bb_[fc], av_[fr], acc[fr][fc], 0, 0, 0); \
    __builtin_amdgcn_s_setprio(0); \
} while (0)

// ---------------- wide GEMM (K=1600, phased): fhb = wideA @ Ucat + bvo ----------------
__global__ __launch_bounds__(256, 2) void wgemm_k(
    const u16* __restrict__ A /*wideA, stride 1600*/, const u16* __restrict__ Bp,
    const float* __restrict__ bias, u16* __restrict__ outB)
{
    __shared__ __attribute__((aligned(16))) u16 Bsw[80 * 328];
    __shared__ __attribute__((aligned(16))) u16 As3[3][128 * 32];
    const int tid = threadIdx.x;
    const int wf = tid >> 6, lane = tid & 63;
    const int tl = lane & 15, thi = lane >> 4;
    const int bid = blockIdx.x;
    const int gid = (bid & 7) * ((int)gridDim.x >> 3) + (bid >> 3);
    const long m0 = (long)(gid >> 2) * 128;
    const int q = gid & 3;
    const int n0 = q * 80;
    const int wf_u = __builtin_amdgcn_readfirstlane(wf);
    const u16* BsrcQ = Bp + (long)q * (5 * BQ_U16);

    const int r1 = tid >> 2;
    const int g1 = (tid & 3) ^ ((r1 >> 1) & 3);
    const u16* gA0 = A + (m0 + r1) * 1600L + g1 * 8;
    const u16* gA1 = A + (m0 + 64 + r1) * 1600L + g1 * 8;

    f32x4 acc[2][5];
    #pragma unroll
    for (int i = 0; i < 2; ++i)
        #pragma unroll
        for (int j = 0; j < 5; ++j) acc[i][j] = (f32x4)(0.f);
    const int ar0 = (wf * 32 + tl) * 32 + (thi ^ ((tl >> 1) & 3)) * 8;
    const int br0 = tl * 328 + thi * 8;

    #pragma unroll
    for (int ph = 0; ph < 5; ++ph) {
        if (ph) __syncthreads();
        const u16* Bsrc = BsrcQ + ph * BQ_U16;
        #pragma unroll
        for (int i = 0; i < 13; ++i) {
            int t = i * 256 + tid;
            if (t < 3280)
                GLOAD16(Bsrc + (long)t * 8, &Bsw[(i * 256 + wf_u * 64) * 8]);
        }
        const long ko = (long)ph * 320;

#define WSTAGE(KB) { \
    GLOAD16(gA0 + ko + (KB) * 32, &As3[(KB) % 3][wf_u * 512]); \
    GLOAD16(gA1 + ko + (KB) * 32, &As3[(KB) % 3][2048 + wf_u * 512]); }

        WSTAGE(0); WSTAGE(1);

#define WSTEP(KB, VN) { \
    asm volatile("s_waitcnt vmcnt(" #VN ")" ::: "memory"); \
    __builtin_amdgcn_s_barrier(); \
    __builtin_amdgcn_sched_barrier(0); \
    if ((KB) + 2 < 10) WSTAGE((KB) + 2); \
    TCOMP(KB, (&As3[(KB) % 3][0])); }

        WSTEP(0, 2) WSTEP(1, 2) WSTEP(2, 2) WSTEP(3, 2) WSTEP(4, 2)
        WSTEP(5, 2) WSTEP(6, 2) WSTEP(7, 2) WSTEP(8, 2) WSTEP(9, 0)
#undef WSTEP
#undef WSTAGE
    }

    #pragma unroll
    for (int fr = 0; fr < 2; ++fr) {
        const long row = m0 + wf * 32 + fr * 16 + tl;
        #pragma unroll
        for (int fc = 0; fc < 5; ++fc) {
            const int c0 = n0 + fc * 16 + thi * 4;
            f32x4 v = acc[fr][fc];
            const float4 bs = *(const float4*)&bias[c0];
            v[0] += bs.x; v[1] += bs.y; v[2] += bs.z; v[3] += bs.w;
            uint2 p;
            p.x = (u32)f2b(v[0]) | ((u32)f2b(v[1]) << 16);
            p.y = (u32)f2b(v[2]) | ((u32)f2b(v[3]) << 16);
            *(uint2*)&outB[row * 320 + c0] = p;
        }
    }
}

// ---------------- fused attention on raw h ----------------
__global__ __launch_bounds__(256) void attn2_k(
    const u16* __restrict__ qg, const u16* __restrict__ hcur,
    const int* __restrict__ mail, u16* __restrict__ wideA)
{
    const int tid = threadIdx.x;
    const long n = (long)blockIdx.x * 4 + (tid >> 6);
    const int lane = tid & 63;
    const bool act = lane < 40;
    const int ll = act ? lane : 39;

    int idx[8];
    #pragma unroll
    for (int j = 0; j < 8; ++j) idx[j] = mail[n * 8 + j];
    uint4 hr[8];
    #pragma unroll
    for (int j = 0; j < 8; ++j)
        hr[j] = *(const uint4*)&hcur[(long)idx[j] * 320 + ll * 8];
    uint4 qv[4];
    #pragma unroll
    for (int h = 0; h < 4; ++h)
        qv[h] = *(const uint4*)&qg[n * 1280 + h * 320 + ll * 8];
    if (!act) {
        #pragma unroll
        for (int j = 0; j < 8; ++j) hr[j] = make_uint4(0, 0, 0, 0);
    }

    float qf[4][8];
    #pragma unroll
    for (int h = 0; h < 4; ++h) {
        const u32 w[4] = {qv[h].x, qv[h].y, qv[h].z, qv[h].w};
        #pragma unroll
        for (int p = 0; p < 4; ++p) {
            qf[h][2 * p]     = b2f((u16)(w[p] & 0xFFFF));
            qf[h][2 * p + 1] = b2f((u16)(w[p] >> 16));
        }
    }

    float s[4][8];
    #pragma unroll
    for (int j = 0; j < 8; ++j) {
        float hf[8];
        const u32 w[4] = {hr[j].x, hr[j].y, hr[j].z, hr[j].w};
        #pragma unroll
        for (int p = 0; p < 4; ++p) {
            hf[2 * p]     = b2f((u16)(w[p] & 0xFFFF));
            hf[2 * p + 1] = b2f((u16)(w[p] >> 16));
        }
        #pragma unroll
        for (int h = 0; h < 4; ++h) {
            float d = 0.f;
            #pragma unroll
            for (int m = 0; m < 8; ++m) d += qf[h][m] * hf[m];
            d += __shfl_xor(d, 32, 64);
            d += __shfl_xor(d, 16, 64);
            d += __shfl_xor(d, 8, 64);
            d += __shfl_xor(d, 4, 64);
            d += __shfl_xor(d, 2, 64);
            d += __shfl_xor(d, 1, 64);
            s[h][j] = d;
        }
    }

    float p_[4][8];
    #pragma unroll
    for (int h = 0; h < 4; ++h) {
        float mx = s[h][0];
        #pragma unroll
        for (int j = 1; j < 8; ++j) mx = fmaxf(mx, s[h][j]);
        float sum = 0.f;
        #pragma unroll
        for (int j = 0; j < 8; ++j) { p_[h][j] = __expf(s[h][j] - mx); sum += p_[h][j]; }
        const float inv = 1.f / sum;
        #pragma unroll
        for (int j = 0; j < 8; ++j) p_[h][j] *= inv;
    }

    float y[4][8];
    #pragma unroll
    for (int h = 0; h < 4; ++h)
        #pragma unroll
        for (int m = 0; m < 8; ++m) y[h][m] = 0.f;
    #pragma unroll
    for (int j = 0; j < 8; ++j) {
        float hf[8];
        const u32 w[4] = {hr[j].x, hr[j].y, hr[j].z, hr[j].w};
        #pragma unroll
        for (int p = 0; p < 4; ++p) {
            hf[2 * p]     = b2f((u16)(w[p] & 0xFFFF));
            hf[2 * p + 1] = b2f((u16)(w[p] >> 16));
        }
        #pragma unroll
        for (int h = 0; h < 4; ++h)
            #pragma unroll
            for (int m = 0; m < 8; ++m) y[h][m] += p_[h][j] * hf[m];
    }
    if (act) {
        #pragma unroll
        for (int h = 0; h < 4; ++h) {
            uint4 o;
            o.x = (u32)f2b(y[h][0]) | ((u32)f2b(y[h][1]) << 16);
            o.y = (u32)f2b(y[h][2]) | ((u32)f2b(y[h][3]) << 16);
            o.z = (u32)f2b(y[h][4]) | ((u32)f2b(y[h][5]) << 16);
            o.w = (u32)f2b(y[h][6]) | ((u32)f2b(y[h][7]) << 16);
            *(uint4*)&wideA[n * 1600 + h * 320 + lane * 8] = o;
        }
    }
}

// ---------------- generic GEMM (64-row tiles) — final 960-K projection only ----------------
#define LOADB(bq, kt1) { const long ko_ = (long)(kt1) << 6; \
    _Pragma("unroll") for (int fc = 0; fc < 5; ++fc) \
      _Pragma("unroll") for (int ks = 0; ks < 2; ++ks) \
        bq[fc][ks] = *(const bf16x8*)(gBw + (long)fc * 16 * KP + ko_ + ks * 32); }

#define READA(lkt) { \
    _Pragma("unroll") for (int fr = 0; fr < 4; ++fr) \
      _Pragma("unroll") for (int ks = 0; ks < 2; ++ks) \
        a[fr][ks] = *(const bf16x8*)&As[(fr * 16 + tl) * 320 + ((((lkt) * 8 + ks * 4 + thi) ^ sx) * 8)]; }

#define DOMFMA(bq) { _Pragma("unroll") for (int fr = 0; fr < 4; ++fr) \
    _Pragma("unroll") for (int fc = 0; fc < 5; ++fc) \
      _Pragma("unroll") for (int ks = 0; ks < 2; ++ks) \
        acc[fr][fc] = __builtin_amdgcn_mfma_f32_16x16x32_bf16(bq[fc][ks], a[fr][ks], acc[fr][fc], 0, 0, 0); }

template<int KP>
__global__ __launch_bounds__(256, 2) void gemm_k(
    const u16* __restrict__ A,
    const u16* __restrict__ BT,
    const float* __restrict__ bias,
    float* __restrict__ outF, int ostride, int ocols)
{
    __shared__ u16 As[64 * 320];
    const int tid = threadIdx.x;
    const int w = tid >> 6, lane = tid & 63;
    const int tl = lane & 15, thi = lane >> 4;
    const int sx = tl & 7;
    const long m0 = (long)blockIdx.x * 64;
    const int w_u = __builtin_amdgcn_readfirstlane(w);

    const u16* gBw = BT + ((long)(w * 80 + tl)) * KP + thi * 8;

    f32x4 acc[4][5];
    #pragma unroll
    for (int i = 0; i < 4; ++i)
        #pragma unroll
        for (int j = 0; j < 5; ++j) acc[i][j] = (f32x4)(0.f);

    constexpr int NCH = KP / 320;
    constexpr int NST = KP >> 6;
    bf16x8 bA[5][2], bB[5][2], a[4][2];

    #pragma unroll
    for (int kb = 0; kb < NCH; ++kb) {
        if (kb) __syncthreads();
        #pragma unroll
        for (int i = 0; i < 10; ++i) {
            const int c = i * 256 + w_u * 64 + lane;
            const int r = c / 40, s = c - r * 40;
            GLOAD16(A + (m0 + r) * (long)KP + kb * 320 + ((s ^ (r & 7)) * 8),
                    &As[(i * 256 + w_u * 64) * 8]);
        }
        if (kb == 0) LOADB(bA, 0);
        __syncthreads();
        #pragma unroll
        for (int lkt = 0; lkt < 5; ++lkt) {
            const int kt = kb * 5 + lkt;
            if (kt + 1 < NST) {
                if (kt & 1) { LOADB(bA, kt + 1); } else { LOADB(bB, kt + 1); }
            }
            READA(lkt);
            if (kt & 1) { DOMFMA(bB); } else { DOMFMA(bA); }
        }
    }

    #pragma unroll
    for (int fr = 0; fr < 4; ++fr) {
        const long row = m0 + fr * 16 + tl;
        #pragma unroll
        for (int fc = 0; fc < 5; ++fc) {
            const int c0 = w * 80 + fc * 16 + thi * 4;
            f32x4 v = acc[fr][fc];
            if (bias && c0 < 300) {
                const float4 bs = *(const float4*)&bias[c0];
                v[0] += bs.x; v[1] += bs.y; v[2] += bs.z; v[3] += bs.w;
            }
            if (c0 < ocols)
                *(float4*)&outF[row * (long)ostride + c0] = make_float4(v[0], v[1], v[2], v[3]);
        }
    }
}

// ---------------- build concat A = [mail_sum | f_h | f] (bf16, N x 960) ----------------
__global__ __launch_bounds__(256) void concat_k(
    const u16* __restrict__ hb, const u16* __restrict__ fhb,
    const float* __restrict__ f, const int* __restrict__ mail,
    u16* __restrict__ Acat)
{
    const long n = blockIdx.x;
    int m[8];
    #pragma unroll
    for (int j = 0; j < 8; ++j) m[j] = mail[n * 8 + j];
    for (int c = threadIdx.x; c < 960; c += 256) {
        float v;
        if (c < 300) {
            float s = 0.f;
            #pragma unroll
            for (int j = 0; j < 8; ++j) s += b2f(hb[(long)m[j] * 320 + c]);
            v = s;
        } else if (c < 600) v = b2f(fhb[n * 320 + (c - 300)]);
        else if (c < 900) v = f[n * 300 + (c - 600)];
        else v = 0.f;
        Acat[n * 960 + c] = f2b(v);
    }
}

extern "C" void kernel_launch(void* const* d_in, const int* in_sizes, int n_in,
                              void* d_out, int out_size, void* d_ws, size_t ws_size,
                              hipStream_t stream)
{
    const int N = N_NODES, E = E_EDGES;
    const float* f    = (const float*)d_in[0];
    const float* x    = (const float*)d_in[1];
    const int*   mail = (const int*)d_in[2];
    const int*   srcx = (const int*)d_in[3];
    const float* Wq = (const float*)d_in[4];   const float* bq = (const float*)d_in[5];
    const float* Wk = (const float*)d_in[6];   /* bk unused (softmax-invariant) */
    const float* Wv = (const float*)d_in[8];   const float* bv = (const float*)d_in[9];
    const float* Wo = (const float*)d_in[10];  const float* bo = (const float*)d_in[11];
    const float* Wmp = (const float*)d_in[12]; const float* bmp = (const float*)d_in[13];
    const float* Wlast = (const float*)d_in[14]; const float* blast = (const float*)d_in[15];
    float* out = (float*)d_out;

    char* ws = (char*)d_ws;
    size_t off = 0;
    auto alloc = [&](size_t b) -> void* {
        void* p = ws + off; off += (b + 255) & ~(size_t)255; return p;
    };
    u16* hb    = (u16*)alloc((size_t)E * 320 * 2);   // bf16(x); final h after iter 1
    u16* hb2   = (u16*)alloc((size_t)E * 320 * 2);   // h after iter 0
    u16* qgb   = (u16*)alloc((size_t)N * 1280 * 2);  // qg
    u16* wideA = (u16*)alloc((size_t)N * 1600 * 2);  // [Ycat(1280) | feat(320)]
    u16* fhb   = (u16*)alloc((size_t)N * 320 * 2);
    u16* FGb   = (u16*)alloc((size_t)N * 320 * 2);   // FG = fhb @ Wmp
    u16* Acat  = (u16*)alloc((size_t)N * 960 * 2);
    u16* WqkS  = (u16*)alloc((size_t)16 * BQ_U16 * 2);
    u16* Wm0S  = (u16*)alloc((size_t)4 * BQ_U16 * 2);
    u16* Wm1S  = (u16*)alloc((size_t)4 * BQ_U16 * 2);
    u16* UcatP = (u16*)alloc((size_t)4 * 5 * BQ_U16 * 2);
    u16* WcatB = (u16*)alloc((size_t)960 * 320 * 2);
    float* bqkF = (float*)alloc(1280 * 4);
    float* bvoF = (float*)alloc(320 * 4);

    // ---- weight preprocessing ----
    {
        wqkq_k<<<(16 * BQ_U16 + 255) / 256, 256, 0, stream>>>(Wq, Wk, WqkS);
        bqk_k<<<5, 256, 0, stream>>>(bq, Wk, bqkF);
        ucatp_k<<<(int)((4L * 5 * BQ_U16 + 255) / 256), 256, 0, stream>>>(Wv, Wo, UcatP);
        bvo_k<<<2, 256, 0, stream>>>(bv, Wo, bo, bvoF);
        int blks = (4 * BQ_U16 + 255) / 256;
        convTq_k<<<blks, 256, 0, stream>>>(Wmp, Wm0S);
        convTq_k<<<blks, 256, 0, stream>>>(Wmp + 90000, Wm1S);
        long totc = (long)320 * 960;
        convT_k<<<(int)((totc + 255) / 256), 256, 0, stream>>>(Wlast, 900, 300, WcatB, 960, totc);
    }
    // ---- activations ----
    {
        long totE = (long)E * 40;
        padconv_k<<<(int)((totE + 255) / 256), 256, 0, stream>>>(x, 300, hb, 320, nullptr, 0, totE);
        long totN = (long)N * 40;
        padconv_k<<<(int)((totN + 255) / 256), 256, 0, stream>>>(f, 300, fhb, 320, wideA + 1280, 1600, totN);
    }

    const int GQG = (N / 512) * 16;  // 1024 (%8==0)
    const int GFG = (N / 512) * 4;   // 256  (%8==0)
    const int GNW = (N / 128) * 4;   // 1024 (wgemm)
    const int GEH = (E / 512) * 4;   // 2048 (%8==0)

    for (int it = 0; it < 2; ++it) {
        const float* bmpi = bmp + it * 300;
        const u16* WmS = it ? Wm1S : Wm0S;
        const u16* hcur = it ? hb2 : hb;
        u16* hnxt = it ? hb : hb2;
        // qg = f_h @ Wqk + bqk
        ngemm16_k<4, 1280><<<GQG, 1024, 0, stream>>>(fhb, WqkS, bqkF, qgb);
        // attention on raw h -> wideA[:,0:1280]
        attn2_k<<<N / 4, 256, 0, stream>>>(qgb, hcur, mail, wideA);
        // f_h' = [Ycat | feat] @ Ucat + bvo   (phased K=1600)
        wgemm_k<<<GNW, 256, 0, stream>>>(wideA, UcatP, bvoF, fhb);
        // feat slot refresh for next iteration
        featcopy_k<<<(int)(((long)N * 40 + 255) / 256), 256, 0, stream>>>(fhb, wideA);
        // FG = f_h' @ Wmp (no bias)
        ngemm16_k<2, 320><<<GFG, 1024, 0, stream>>>(fhb, WmS, nullptr, FGb);
        // h' = relu(x + FG[src] - (hcur@Wmp)[e^1] + bmp)
        hgemm16_k<<<GEH, 1024, 0, stream>>>(hcur, WmS, FGb, hb, srcx, bmpi, hnxt);
    }

    // Acat = [mail_sum | f_h | f]
    concat_k<<<N, 256, 0, stream>>>(hb, fhb, f, mail, Acat);
    // out = Acat @ Wlast + blast
    gemm_k<960><<<N / 64, 256, 0, stream>>>(Acat, WcatB, blast, out, 300, 300);
}